// Round 8
// baseline (114.401 us; speedup 1.0000x reference)
//
#include <hip/hip_runtime.h>
#include <math.h>

#define BB 16
#define CC 6
#define QQ 256
#define TT 256
#define DD 256
#define NPAIR 15                      // C*(C-1)/2 for C=6
#define NBC (BB * CC)                 // 96
#define CONS_BLOCKS (BB * NPAIR * 4)  // 960  (blocks [0, 960))
#define BIG_BLOCKS (NBC * 8)          // 768  (blocks [960, 1728)) — 2048 float4/block
#define MAIN_BLOCKS (CONS_BLOCKS + BIG_BLOCKS)  // 1728 ≤ 2048 → one scheduling round

// ws layout (bytes) — disjoint plain stores only; consumed by k_fin across the
// kernel boundary. (R4: device __threadfence = L2 writeback, ~100ns × blocks.
// R5: same-line float atomics from 2.5k blocks serialize, +35us. Disjoint
// stores + kernel boundary is the free publication path on gfx950.)
//   [0,     3072)  packPart float[96*8]   (score,box,pair,qv,cam per bc)
//   [4096, 10240)  bigPart  float2[768]   (ss, ent per block)
//   [16384,24064)  consPart float2[960]   (cons, nval per block)

__device__ __forceinline__ float block_sum256(float v, float* s_red) {
    #pragma unroll
    for (int off = 32; off > 0; off >>= 1) v += __shfl_xor(v, off, 64);
    __syncthreads();
    if ((threadIdx.x & 63) == 0) s_red[threadIdx.x >> 6] = v;
    __syncthreads();
    return s_red[0] + s_red[1] + s_red[2] + s_red[3];
}

// two values reduced with a single pair of barriers
__device__ __forceinline__ float2 block_sum256x2(float a, float b, float2* s_red2) {
    #pragma unroll
    for (int off = 32; off > 0; off >>= 1) {
        a += __shfl_xor(a, off, 64);
        b += __shfl_xor(b, off, 64);
    }
    __syncthreads();
    if ((threadIdx.x & 63) == 0) s_red2[threadIdx.x >> 6] = make_float2(a, b);
    __syncthreads();
    float2 r;
    r.x = s_red2[0].x + s_red2[1].x + s_red2[2].x + s_red2[3].x;
    r.y = s_red2[0].y + s_red2[1].y + s_red2[2].y + s_red2[3].y;
    return r;
}

__device__ __forceinline__ int read_bool(const void* p, int idx, int fmt) {
    if (fmt == 2) return ((const float*)p)[idx] != 0.0f;
    if (fmt == 1) return ((const unsigned char*)p)[idx] != 0;
    return ((const int*)p)[idx] != 0;
}

// Block-uniform bool-storage-format detection from the first 4096 bytes of
// target_mask (valid window in all 3 formats; L2-hot). 2=f32, 1=u8, 0=i32.
__device__ __forceinline__ int detect_fmt(const void* tm_raw, int* s_cf, int* s_cm) {
    const int t = threadIdx.x;
    if (t == 0) { *s_cf = 0; *s_cm = 0; }
    __syncthreads();
    uint4 w = ((const uint4*)tm_raw)[t];
    unsigned int u4[4] = {w.x, w.y, w.z, w.w};
    int cf = 0, cm = 0;
    #pragma unroll
    for (int k = 0; k < 4; k++) {
        cf += ((u4[k] >> 24) == 0x3Fu);          // 1.0f high byte
        cm += ((u4[k] & 0xFFFFFF00u) != 0u);     // nonzero misaligned byte
    }
    if (cf) atomicAdd(s_cf, cf);
    if (cm) atomicAdd(s_cm, cm);
    __syncthreads();
    return (*s_cf > 16) ? 2 : ((*s_cm > 0) ? 1 : 0);
}

struct PackRes { int count; int rank; int tm; };

// Block-wide stable targets-first pack of camera bc. Writes qid of packed
// slot t to s_out[t] (-1 if invalid); returns {count, rank(t), tm(t)}.
__device__ __forceinline__ PackRes block_pack(const void* tm_raw,
                                              const int* __restrict__ ids,
                                              int bc, int fmt, int cam,
                                              int* s_sids, int* s_wsum,
                                              int* s_out) {
    const int t = threadIdx.x, lane = t & 63, wv = t >> 6;
    const int tm = read_bool(tm_raw, bc * QQ + t, fmt);
    int v = tm;
    #pragma unroll
    for (int off = 1; off < 64; off <<= 1) {
        int u = __shfl_up(v, off, 64);
        if (lane >= off) v += u;
    }
    if (lane == 63) s_wsum[wv] = v;
    __syncthreads();
    const int count = s_wsum[0] + s_wsum[1] + s_wsum[2] + s_wsum[3];
    int woff = 0;
    #pragma unroll
    for (int k = 0; k < 3; k++) woff += (k < wv) ? s_wsum[k] : 0;
    const int excl = woff + v - tm;                      // exclusive scan of tm
    const int rank = tm ? excl : (count + (t - excl));   // stable partition rank
    s_sids[rank] = ids[bc * QQ + t];
    __syncthreads();
    s_out[t] = (t < count && cam) ? s_sids[t] : -1;
    __syncthreads();                                     // s_sids/s_wsum reusable
    PackRes r; r.count = count; r.rank = rank; r.tm = tm;
    return r;
}

// score/box/pair losses for camera bc, given its packed qids + PackRes.
__device__ __forceinline__ void pack_losses(int bc, PackRes pr, int cam,
                                            const int* s_qe,
                                            const float* __restrict__ det_scores,
                                            const float* __restrict__ det_boxes,
                                            const float* __restrict__ boxes,
                                            const float* __restrict__ assoc,
                                            const int* __restrict__ img_h_p,
                                            const int* __restrict__ img_w_p,
                                            float2* s_red2,
                                            float* __restrict__ packPart) {
    const int t = threadIdx.x;
    const int j = t;                    // packed slot for score/pair
    const int qid = s_qe[j];            // >=0 iff (j < count && cam)
    float score_sum = 0.0f, box_sum = 0.0f, pair_sum = 0.0f;
    if (cam) {
        float p = det_scores[(size_t)bc * QQ + j];
        p = fminf(fmaxf(p, 1e-6f), 1.0f - 1e-6f);
        score_sum = (j < pr.count) ? -__logf(p) : -__logf(1.0f - p);
    }
    if (qid >= 0) {
        int slot = qid & (TT - 1);
        float a = assoc[((size_t)bc * QQ + j) * TT + slot];
        pair_sum = -__logf(fmaxf(a, 1e-8f));
    }
    if (pr.tm && cam) {
        const int jj = pr.rank;         // packed slot of original query t
        const float iw = (float)img_w_p[0], ih = (float)img_h_p[0];
        const float* bx = boxes + ((size_t)bc * QQ + t) * 4;
        const float* db = det_boxes + ((size_t)bc * QQ + jj) * 4;
        float b0 = fminf(fmaxf(bx[0] / iw, 0.0f), 1.0f);
        float b1 = fminf(fmaxf(bx[1] / ih, 0.0f), 1.0f);
        float b2 = fminf(fmaxf(bx[2] / iw, 0.0f), 1.0f);
        float b3 = fminf(fmaxf(bx[3] / ih, 0.0f), 1.0f);
        box_sum = fabsf(db[0] - b0) + fabsf(db[1] - b1) +
                  fabsf(db[2] - b2) + fabsf(db[3] - b3);
    }
    float2 r1 = block_sum256x2(score_sum, box_sum, s_red2);
    float2 r2 = block_sum256x2(pair_sum, 0.0f, s_red2);
    if (t == 0) {
        float* row = packPart + bc * 8;
        row[0] = r1.x; row[1] = r1.y; row[2] = r2.x;
        row[3] = cam ? (float)pr.count : 0.0f;
        row[4] = (float)cam;
    }
}

// ---------------------------------------------------------------------------
// Kernel 1 — one dispatch, whole grid co-resident (1728 ≤ 2048 blocks @ 8/CU):
//   [0, 960):    consistency term; the qg==0 blocks of pairs (0,1),(2,3),(4,5)
//                also emit both cameras' pack losses (they have both packed
//                qid sets in LDS already) — covers all 96 (b,c) rows.
//   [960, 1728): det_norm ss + cam-masked entropy (2048-float4 chunks,
//                bc-aligned so cam is block-uniform).
// __launch_bounds__(256,8): cap at 64 VGPR so 8 blocks/CU fit (one round).
// ---------------------------------------------------------------------------
__global__ __launch_bounds__(256, 8)
void k_main(const float4* __restrict__ tok,
            const float* __restrict__ assoc,
            const float* __restrict__ det_scores,
            const float* __restrict__ det_boxes,
            const float* __restrict__ boxes,
            const void* __restrict__ cam_raw,
            const void* __restrict__ tm_raw,
            const int* __restrict__ ids,
            const int* __restrict__ img_h_p,
            const int* __restrict__ img_w_p,
            float* __restrict__ packPart,
            float* __restrict__ bigPart,
            float* __restrict__ consPart) {
    const int blk = blockIdx.x;
    const int t = threadIdx.x, lane = t & 63, wv = t >> 6;
    __shared__ int s_cf, s_cm;
    __shared__ float2 s_red2[4];

    if (blk >= CONS_BLOCKS) {
        // ---- big phase: 2048 float4s of tok & assoc, bc-aligned ----
        const int bb = blk - CONS_BLOCKS;
        const int bc = bb >> 3;
        const long base = (long)bc * 16384 + (long)(bb & 7) * 2048 + t;
        const float4* asc = (const float4*)assoc;
        const int fmt = detect_fmt(tm_raw, &s_cf, &s_cm);
        const int cam = read_bool(cam_raw, bc, fmt);

        float ss = 0.0f, ent = 0.0f;
        #pragma unroll 1                   // keep VGPR ≤ 64; 4 loads in flight,
        for (int h = 0; h < 4; h++) {      // 32 waves/CU give the MLP
            const long o = base + h * 512;
            float4 t0 = tok[o], t1 = tok[o + 256];
            float4 a0 = asc[o], a1 = asc[o + 256];
            ss += t0.x * t0.x + t0.y * t0.y + t0.z * t0.z + t0.w * t0.w
                + t1.x * t1.x + t1.y * t1.y + t1.z * t1.z + t1.w * t1.w;
            if (cam) {                     // block-uniform branch
                ent -= a0.x * __logf(fmaxf(a0.x, 1e-8f)) + a0.y * __logf(fmaxf(a0.y, 1e-8f))
                     + a0.z * __logf(fmaxf(a0.z, 1e-8f)) + a0.w * __logf(fmaxf(a0.w, 1e-8f));
                ent -= a1.x * __logf(fmaxf(a1.x, 1e-8f)) + a1.y * __logf(fmaxf(a1.y, 1e-8f))
                     + a1.z * __logf(fmaxf(a1.z, 1e-8f)) + a1.w * __logf(fmaxf(a1.w, 1e-8f));
            }
        }
        float2 r = block_sum256x2(ss, ent, s_red2);
        if (t == 0) { bigPart[bb * 2] = r.x; bigPart[bb * 2 + 1] = r.y; }

    } else {
        // ---- cons phase: one block per (b, pair, qgroup-of-64) ----
        const int cb = blk;
        const int qg = cb & 3;
        const int bp = cb >> 2;             // b*NPAIR + pair
        const int b = bp / NPAIR;
        const int pi = bp % NPAIR;
        int c = 0, d = 1;
        {
            int k = pi, cc;
            for (cc = 0; cc < CC - 1; cc++) {
                int span = CC - 1 - cc;
                if (k < span) { c = cc; d = cc + 1 + k; break; }
                k -= span;
            }
        }
        __shared__ int s_sids[QQ], s_qc[QQ], s_qd[QQ], s_wsum[4];
        const int fmt = detect_fmt(tm_raw, &s_cf, &s_cm);
        const int cam_c = read_bool(cam_raw, b * CC + c, fmt);
        const int cam_d = read_bool(cam_raw, b * CC + d, fmt);
        PackRes prc = block_pack(tm_raw, ids, b * CC + c, fmt, cam_c, s_sids, s_wsum, s_qc);
        PackRes prd = block_pack(tm_raw, ids, b * CC + d, fmt, cam_d, s_sids, s_wsum, s_qd);

        const int qd0 = s_qd[lane];
        const int qd1 = s_qd[64 + lane];
        const int qd2 = s_qd[128 + lane];
        const int qd3 = s_qd[192 + lane];
        const float4* assoc_c = (const float4*)(assoc + (size_t)(b * CC + c) * QQ * TT);
        const float4* assoc_d = (const float4*)(assoc + (size_t)(b * CC + d) * QQ * TT);

        float tot = 0.0f, nval = 0.0f;
        for (int qi = 0; qi < 16; qi++) {
            const int id = s_qc[qg * 64 + wv * 16 + qi];   // wave-uniform
            if (id < 0) continue;
            unsigned long long m0 = __ballot(qd0 == id);
            unsigned long long m1 = __ballot(qd1 == id);
            unsigned long long m2 = __ballot(qd2 == id);
            unsigned long long m3 = __ballot(qd3 == id);
            int cnt = __popcll(m0) + __popcll(m1) + __popcll(m2) + __popcll(m3);
            if (cnt == 0) continue;
            const int q = qg * 64 + wv * 16 + qi;
            float4 r = assoc_c[(size_t)q * (TT / 4) + lane];
            float ax = 0.0f, ay = 0.0f, az = 0.0f, aw = 0.0f;
            unsigned long long mm[4] = {m0, m1, m2, m3};
            #pragma unroll
            for (int kk = 0; kk < 4; kk++) {
                unsigned long long m = mm[kk];
                while (m) {
                    int p = kk * 64 + __builtin_ctzll(m);
                    m &= m - 1;
                    float4 vv = assoc_d[(size_t)p * (TT / 4) + lane];
                    ax += vv.x; ay += vv.y; az += vv.z; aw += vv.w;
                }
            }
            float inv = 1.0f / (float)cnt;
            float dx = r.x - ax * inv, dy = r.y - ay * inv;
            float dz = r.z - az * inv, dw = r.w - aw * inv;
            tot += dx * dx + dy * dy + dz * dz + dw * dw;
            nval += 1.0f;
        }
        float2 r2 = block_sum256x2(tot, nval, s_red2);
        if (t == 0) {
            consPart[cb * 2] = r2.x * (1.0f / TT);
            consPart[cb * 2 + 1] = r2.y;
        }

        // ---- pack-loss epilogue on 3 designated blocks per b ----
        // pairs (0,1)=pi0, (2,3)=pi9, (4,5)=pi14 cover all 6 cameras.
        if (qg == 0 && (pi == 0 || pi == 9 || pi == 14)) {
            pack_losses(b * CC + c, prc, cam_c, s_qc, det_scores, det_boxes,
                        boxes, assoc, img_h_p, img_w_p, s_red2, packPart);
            pack_losses(b * CC + d, prd, cam_d, s_qd, det_scores, det_boxes,
                        boxes, assoc, img_h_p, img_w_p, s_red2, packPart);
        }
    }
}

// ---------------------------------------------------------------------------
// Kernel 2: finalize — reduce all partial arrays (~14 KB, L2-hot), 1 block.
// ---------------------------------------------------------------------------
__global__ __launch_bounds__(256)
void k_fin(const float* __restrict__ packPart, const float2* __restrict__ bigPart,
           const float2* __restrict__ consPart, float* __restrict__ out) {
    const int t = threadIdx.x;
    __shared__ float s_red[4];
    float sc = 0, bx = 0, pr = 0, qv = 0, cm = 0;
    if (t < NBC) {
        const float* row = packPart + t * 8;
        sc = row[0]; bx = row[1]; pr = row[2]; qv = row[3]; cm = row[4];
    }
    float ss = 0, ent = 0;
    #pragma unroll
    for (int k = 0; k < BIG_BLOCKS / 256; k++) {
        float2 v = bigPart[k * 256 + t];
        ss += v.x; ent += v.y;
    }
    float cons = 0, nval = 0;
    for (int i = t; i < CONS_BLOCKS; i += 256) {
        float2 v = consPart[i];
        cons += v.x; nval += v.y;
    }
    sc = block_sum256(sc, s_red);
    bx = block_sum256(bx, s_red);
    pr = block_sum256(pr, s_red);
    qv = block_sum256(qv, s_red);
    cm = block_sum256(cm, s_red);
    ss = block_sum256(ss, s_red);
    ent = block_sum256(ent, s_red);
    cons = block_sum256(cons, s_red);
    nval = block_sum256(nval, s_red);
    if (t == 0) {
        float det_norm = ss / (float)((long)BB * CC * QQ * DD);
        float denom_cam = fmaxf(cm * (float)QQ, 1.0f);
        float score_loss = sc / denom_cam;
        float box_loss = bx / fmaxf(4.0f * qv, 1.0f);
        float det_sup = score_loss + box_loss;
        float ent_loss = ent / denom_cam;
        float pair_loss = pr / fmaxf(qv, 1.0f);
        float cons_loss = cons / fmaxf(nval, 1.0f);
        out[0] = det_norm + det_sup + ent_loss + pair_loss + cons_loss;
        out[1] = det_norm;
        out[2] = det_sup;
        out[3] = ent_loss;
        out[4] = pair_loss;
        out[5] = cons_loss;
    }
}

extern "C" void kernel_launch(void* const* d_in, const int* in_sizes, int n_in,
                              void* d_out, int out_size, void* d_ws, size_t ws_size,
                              hipStream_t stream) {
    const float* det_tokens = (const float*)d_in[0];
    const float* det_scores = (const float*)d_in[1];
    const float* det_boxes  = (const float*)d_in[2];
    const float* assoc      = (const float*)d_in[3];
    const float* boxes      = (const float*)d_in[4];
    const void*  cam_raw    = d_in[5];
    const void*  tm_raw     = d_in[6];
    const int*   ids        = (const int*)d_in[7];
    const int*   img_h      = (const int*)d_in[8];
    const int*   img_w      = (const int*)d_in[9];

    char* ws = (char*)d_ws;
    float* packPart = (float*)(ws + 0);
    float* bigPart  = (float*)(ws + 4096);
    float* consPart = (float*)(ws + 16384);

    k_main<<<MAIN_BLOCKS, 256, 0, stream>>>((const float4*)det_tokens, assoc,
                                            det_scores, det_boxes, boxes,
                                            cam_raw, tm_raw, ids, img_h, img_w,
                                            packPart, bigPart, consPart);
    k_fin<<<1, 256, 0, stream>>>(packPart, (const float2*)bigPart,
                                 (const float2*)consPart, (float*)d_out);
}